// Round 11
// baseline (198.112 us; speedup 1.0000x reference)
//
#include <hip/hip_runtime.h>
#include <math.h>

#define EPS 1e-8f
#define LAMBDA 1e-3f
#define LOG2E 1.44269504088896f
#define LN2 0.693147180559945f

#define SCHED_FENCE() __builtin_amdgcn_sched_barrier(0)

typedef float f2 __attribute__((ext_vector_type(2)));
typedef unsigned int u32v2 __attribute__((ext_vector_type(2)));
__device__ __forceinline__ f2 f2s(float x) { return (f2){x, x}; }
__device__ __forceinline__ f2 pkfma(f2 a, f2 b, f2 c) {
  return __builtin_elementwise_fma(a, b, c);
}

// fast transcendentals (raw HW ops, log2 domain)
#if __has_builtin(__builtin_amdgcn_exp2f)
__device__ __forceinline__ float exp2_fast(float x) { return __builtin_amdgcn_exp2f(x); }
#else
__device__ __forceinline__ float exp2_fast(float x) { float r; asm("v_exp_f32 %0, %1" : "=v"(r) : "v"(x)); return r; }
#endif
#if __has_builtin(__builtin_amdgcn_logf)
__device__ __forceinline__ float log2_fast(float x) { return __builtin_amdgcn_logf(x); }
#else
__device__ __forceinline__ float log2_fast(float x) { float r; asm("v_log_f32 %0, %1" : "=v"(r) : "v"(x)); return r; }
#endif

// DPP lane-permute: executes in the VALU pipe (no LDS round trip).
template <int CTRL>
__device__ __forceinline__ float dppmov(float v) {
  return __int_as_float(__builtin_amdgcn_update_dpp(
      0, __float_as_int(v), CTRL, 0xF, 0xF, true));
}

// xor16 / xor32 lane exchanges (gfx950 permlane*_swap = VALU; fallbacks portable)
#if __has_builtin(__builtin_amdgcn_permlane16_swap)
__device__ __forceinline__ float sum_x16(float v) {
  u32v2 r = __builtin_amdgcn_permlane16_swap(__float_as_uint(v), __float_as_uint(v), false, false);
  return __uint_as_float(r.x) + __uint_as_float(r.y);
}
__device__ __forceinline__ float max_x16(float v) {
  u32v2 r = __builtin_amdgcn_permlane16_swap(__float_as_uint(v), __float_as_uint(v), false, false);
  return fmaxf(__uint_as_float(r.x), __uint_as_float(r.y));
}
#else
__device__ __forceinline__ float sum_x16(float v) {
  return v + __int_as_float(__builtin_amdgcn_ds_swizzle(__float_as_int(v), 0x401F));
}
__device__ __forceinline__ float max_x16(float v) {
  return fmaxf(v, __int_as_float(__builtin_amdgcn_ds_swizzle(__float_as_int(v), 0x401F)));
}
#endif
#if __has_builtin(__builtin_amdgcn_permlane32_swap)
__device__ __forceinline__ float sum_x32(float v) {
  u32v2 r = __builtin_amdgcn_permlane32_swap(__float_as_uint(v), __float_as_uint(v), false, false);
  return __uint_as_float(r.x) + __uint_as_float(r.y);
}
#else
__device__ __forceinline__ float sum_x32(float v) { return v + __shfl_xor(v, 32, 64); }
#endif

__device__ __forceinline__ float redsum32(float v) {
  v += dppmov<0xB1>(v);    // xor 1
  v += dppmov<0x4E>(v);    // xor 2
  v += dppmov<0x141>(v);   // xor 7
  v += dppmov<0x140>(v);   // xor 15
  return sum_x16(v);       // xor 16
}
__device__ __forceinline__ float redmax32(float v) {
  v = fmaxf(v, dppmov<0xB1>(v));
  v = fmaxf(v, dppmov<0x4E>(v));
  v = fmaxf(v, dppmov<0x141>(v));
  v = fmaxf(v, dppmov<0x140>(v));
  return max_x16(v);
}

// 4x4 pose matmul on packed f2 lanes: v2[8] = x(4x4) @ w(4x4), row-major.
__device__ __forceinline__ void mat8(const float* __restrict__ xrow,
                                     float4 w0, float4 w1, float4 w2, float4 w3,
                                     f2 (&v2)[8]) {
  const float4* xp = reinterpret_cast<const float4*>(xrow);
  float4 xv0 = xp[0], xv1 = xp[1], xv2_ = xp[2], xv3 = xp[3];
  f2 w0a = {w0.x, w0.y}, w0b = {w0.z, w0.w};
  f2 w1a = {w1.x, w1.y}, w1b = {w1.z, w1.w};
  f2 w2a = {w2.x, w2.y}, w2b = {w2.z, w2.w};
  f2 w3a = {w3.x, w3.y}, w3b = {w3.z, w3.w};
  {
    f2 ta = f2s(xv0.x) * w0a; f2 tb = f2s(xv0.x) * w0b;
    ta = pkfma(f2s(xv0.y), w1a, ta); tb = pkfma(f2s(xv0.y), w1b, tb);
    ta = pkfma(f2s(xv0.z), w2a, ta); tb = pkfma(f2s(xv0.z), w2b, tb);
    v2[0] = pkfma(f2s(xv0.w), w3a, ta); v2[1] = pkfma(f2s(xv0.w), w3b, tb);
  }
  {
    f2 ta = f2s(xv1.x) * w0a; f2 tb = f2s(xv1.x) * w0b;
    ta = pkfma(f2s(xv1.y), w1a, ta); tb = pkfma(f2s(xv1.y), w1b, tb);
    ta = pkfma(f2s(xv1.z), w2a, ta); tb = pkfma(f2s(xv1.z), w2b, tb);
    v2[2] = pkfma(f2s(xv1.w), w3a, ta); v2[3] = pkfma(f2s(xv1.w), w3b, tb);
  }
  {
    f2 ta = f2s(xv2_.x) * w0a; f2 tb = f2s(xv2_.x) * w0b;
    ta = pkfma(f2s(xv2_.y), w1a, ta); tb = pkfma(f2s(xv2_.y), w1b, tb);
    ta = pkfma(f2s(xv2_.z), w2a, ta); tb = pkfma(f2s(xv2_.z), w2b, tb);
    v2[4] = pkfma(f2s(xv2_.w), w3a, ta); v2[5] = pkfma(f2s(xv2_.w), w3b, tb);
  }
  {
    f2 ta = f2s(xv3.x) * w0a; f2 tb = f2s(xv3.x) * w0b;
    ta = pkfma(f2s(xv3.y), w1a, ta); tb = pkfma(f2s(xv3.y), w1b, tb);
    ta = pkfma(f2s(xv3.z), w2a, ta); tb = pkfma(f2s(xv3.z), w2b, tb);
    v2[6] = pkfma(f2s(xv3.w), w3a, ta); v2[7] = pkfma(f2s(xv3.w), w3b, tb);
  }
}

template <bool V> struct BoolC { static constexpr bool value = V; };

// One block per output row n (508 rows). 512 threads = 16 chunks x 32 c.
// Thread (chunk,c) owns output capsule c for B in [chunk*18, chunk*18+18).
//
// ROUND-11 FIX: rounds 9/10 spilled (VGPR 128-cap, 100+ MB scratch) even
// after the w-hoist was removed. Mechanism: deleting the 3rd barrier per
// pass merged each fully-unrolled pass with the previous finalize into ONE
// scheduling region; LLVM hoisted next-pass loads across the old boundary
// and live ranges blew past the cap. sched_barrier(0) restores the fences
// at zero runtime cost (no instruction emitted) while keeping the
// barrier-count win (2 __syncthreads/pass instead of 3).
//
// launch_bounds(512, 2): empirically caps VGPR at 128 (2 blocks/CU);
// (512,4) forced a 64-cap and spilled (rounds 0-2). Spills show as
// WRITE_SIZE above the 19.4 MB output floor / FETCH above ~4.9 MB.
__launch_bounds__(512, 2)
__global__ void convcaps_kernel(const float* __restrict__ x,
                                const float* __restrict__ wgl,
                                const float* __restrict__ beta_u,
                                const float* __restrict__ beta_a,
                                float* __restrict__ out) {
  __shared__ float xr[288][16];       // pose patches, 18 KB
  __shared__ float a_sh[288];         // a/(a+EPS)
  __shared__ f2 red2[17][256];        // per-wave partials: A1[8] A2[8] (f2), S in [16].x
  __shared__ float mu_l[32][18];      // +2 pad: rows 8B-aligned for b64 reads
  __shared__ float i2s_l[32][18];     // LOG2E/(2*sigma)
  __shared__ float hl_l[32][18];      // 0.5*ln(sigma)
  __shared__ float S_l[32];

  const int tid = threadIdx.x;
  const int n = blockIdx.x;
  const int c = tid & 31;
  const int chunk = tid >> 5;         // 0..15

  // ---- stage 9 source rows (float4): xr[B][s], a_sh[B] ----
  for (int idx = tid; idx < 1224; idx += 512) {   // 9 * 136 float4
    int t = idx / 136;
    int e4 = idx - t * 136;
    int g = 9 * n + t;
    int bg = g / 2286;                 // 2286 = 9*254
    int ki = (g % 2286) / 762;         // 762 = 3*254
    int owp = g % 254;
    const float4* src = reinterpret_cast<const float4*>(x) +
                        (size_t)((bg * 256 + ki + owp) * 4) * 136;
    float4 val = src[e4];
    if (e4 < 128) reinterpret_cast<float4*>(&xr[0][0])[t * 128 + e4] = val;
    else          reinterpret_cast<float4*>(a_sh)[t * 8 + (e4 - 128)] = val;
  }
  __syncthreads();
  for (int e = tid; e < 288; e += 512) { float a = a_sh[e]; a_sh[e] = a / (a + EPS); }
  __syncthreads();
  SCHED_FENCE();

  f2 A1[8], A2[8];
  float Ssum;
  f2 m2[8], i2s2[8];                  // m2 = -2*mu*i2s; i2s pre-scaled LOG2E
  float bias3 = 0.f;
  const int Bbase = chunk * 18;
  const float4* wp = reinterpret_cast<const float4*>(wgl) + ((size_t)(Bbase * 32 + c)) * 4;
  float* rowout = out + 276352 + ((size_t)n * 288 + Bbase) * 32 + c;   // r output

  auto ldw = [&](int i, float4& b0, float4& b1, float4& b2, float4& b3) {
    const float4* nx = wp + (size_t)i * 128;
    b0 = nx[0]; b1 = nx[1]; b2 = nx[2]; b3 = nx[3];
  };

  auto accum = [&](const f2 (&v2)[8], float wgt) {
    f2 wg = f2s(wgt);
    #pragma unroll
    for (int j = 0; j < 8; ++j) {
      f2 p = wg * v2[j];
      A1[j] += p;
      A2[j] = pkfma(p, v2[j], A2[j]);
    }
    Ssum += wgt;
  };

  auto qexp = [&](const f2 (&v2)[8]) -> float {
    f2 qa = {0.f, 0.f}, qb = {0.f, 0.f};
    #pragma unroll
    for (int j = 0; j < 8; j += 2) {
      f2 t0 = pkfma(v2[j], i2s2[j], m2[j]);
      qa = pkfma(v2[j], t0, qa);
      f2 t1 = pkfma(v2[j + 1], i2s2[j + 1], m2[j + 1]);
      qb = pkfma(v2[j + 1], t1, qb);
    }
    float acc = (qa.x + qb.x) + (qa.y + qb.y);
    return exp2_fast(bias3 - acc);      // lnap <= 0, log2 domain
  };

  // finalize: 2 barriers (red publish, stats publish). No aout section.
  auto finalize = [&]() {
    SCHED_FENCE();                      // keep finalize a separate region
    #pragma unroll
    for (int j = 0; j < 8; ++j) {
      A1[j].x = sum_x32(A1[j].x);
      A1[j].y = sum_x32(A1[j].y);
      A2[j].x = sum_x32(A2[j].x);
      A2[j].y = sum_x32(A2[j].y);
    }
    Ssum = sum_x32(Ssum);
    if ((tid & 63) < 32) {
      int col = (tid >> 6) * 32 + c;
      #pragma unroll
      for (int j = 0; j < 8; ++j) {     // f2 stores: 17 ds_write_b64
        red2[j][col] = A1[j];
        red2[8 + j][col] = A2[j];
      }
      reinterpret_cast<float*>(&red2[16][col])[0] = Ssum;
    }
    __syncthreads();
    {
      int s = tid >> 5;
      int c2 = tid & 31;
      const float* redf = reinterpret_cast<const float*>(&red2[0][0]);
      int o1 = (s >> 1) * 512 + c2 * 2 + (s & 1);
      float a1 = 0.f, a2 = 0.f, ss = 0.f;
      #pragma unroll
      for (int ch = 0; ch < 8; ++ch) {
        int off = ch * 64;               // col step 32 -> 64 dwords
        a1 += redf[o1 + off];
        a2 += redf[o1 + 8 * 512 + off];
        ss += redf[16 * 512 + c2 * 2 + off];
      }
      float inv = __builtin_amdgcn_rcpf(ss + EPS);
      float m = a1 * inv;
      float Sc = ss * inv;
      float sg = fmaf(-m * m, 2.0f - Sc, a2 * inv) + EPS;   // sigma_sq
      mu_l[c2][s] = m;
      i2s_l[c2][s] = (0.5f * LOG2E) * __builtin_amdgcn_rcpf(sg);  // log2 domain
      hl_l[c2][s] = 0.5f * __logf(sg);
      if (s == 0) S_l[c2] = ss;
    }
    __syncthreads();
    SCHED_FENCE();                      // stop next pass hoisting into here
  };

  // ================= pass 0: wgt = a/32, no softmax =================
  {
    #pragma unroll
    for (int j = 0; j < 8; ++j) { A1[j] = (f2){0.f, 0.f}; A2[j] = (f2){0.f, 0.f}; }
    Ssum = 0.f;
    #pragma unroll
    for (int i = 0; i < 18; ++i) {
      float4 w0, w1, w2, w3;
      ldw(i, w0, w1, w2, w3);
      f2 v2[8];
      mat8(&xr[Bbase + i][0], w0, w1, w2, w3, v2);
      accum(v2, a_sh[Bbase + i] * 0.03125f);
    }
    finalize();
  }

  // ================= passes 1,2: fully-unrolled softmax loop =================
  auto em_pass = [&](auto storeC) {
    constexpr bool doStore = decltype(storeC)::value;
    #pragma unroll
    for (int j = 0; j < 8; ++j) { A1[j] = (f2){0.f, 0.f}; A2[j] = (f2){0.f, 0.f}; }
    Ssum = 0.f;
    {
      const f2* murow = reinterpret_cast<const f2*>(&mu_l[c][0]);
      const f2* isrow = reinterpret_cast<const f2*>(&i2s_l[c][0]);
      const f2* hlrow = reinterpret_cast<const f2*>(&hl_l[c][0]);
      f2 kacc = {0.f, 0.f};
      float Hl = 0.f;
      #pragma unroll
      for (int j = 0; j < 8; ++j) {
        f2 mu = murow[j];
        f2 is = isrow[j];
        i2s2[j] = is;
        f2 mis = mu * is;
        m2[j] = f2s(-2.f) * mis;
        kacc = pkfma(mis, mu, kacc);        // sum mu^2*i2s (log2 domain)
        f2 h = hlrow[j];
        Hl += h.x + h.y;
      }
      // inline ln(a_out): cost=(bu*16+Hl)*S; lnao = -ln(1+exp(-z)) via log2
      float S = S_l[c];
      float cost = fmaf(beta_u[c], 16.0f, Hl) * S;
      float z = LAMBDA * (beta_a[c] - cost);
      float u = 1.0f + exp2_fast(-z * LOG2E);
      float lnao = -LN2 * log2_fast(u);
      float bias = lnao - Hl;
      bias -= redmax32(bias);               // once per pass: lnap <= 0 always
      bias3 = bias * LOG2E - (kacc.x + kacc.y);
    }
    SCHED_FENCE();                          // bias-prep | main loop boundary

    f2 vb0[8], vb1[8];                      // parity banks, literal-indexed
    float wg0 = 0.f, wg1 = 0.f;
    #pragma unroll
    for (int i = 0; i < 18; ++i) {          // i is a literal after unroll
      f2 (&v2)[8] = (i & 1) ? vb1 : vb0;
      float4 w0, w1, w2, w3;
      ldw(i, w0, w1, w2, w3);
      mat8(&xr[Bbase + i][0], w0, w1, w2, w3, v2);
      float af = a_sh[Bbase + i];
      float e = qexp(v2);
      float se = redsum32(e);
      if (i > 0) {                          // fill the reduce's dep shadow
        f2 (&pv)[8] = ((i - 1) & 1) ? vb1 : vb0;
        accum(pv, ((i - 1) & 1) ? wg1 : wg0);
      }
      float t = __builtin_amdgcn_rcpf(se + 1e-35f);
      float r2 = e * t;
      if (doStore) rowout[(size_t)i * 32] = r2;
      ((i & 1) ? wg1 : wg0) = r2 * af;
    }
    accum(vb1, wg1);                        // i = 17 is odd -> bank 1
    finalize();
  };
  em_pass(BoolC<false>{});
  em_pass(BoolC<true>{});

  // ---- outputs: row n = [mu (512) | a_out (32)], coalesced ----
  {
    int c2 = tid >> 4;
    int s = tid & 15;
    out[(size_t)n * 544 + tid] = mu_l[c2][s];
  }
  if (tid < 32) {                     // a_out from pass-2 stats (c == tid)
    float sh = 0.f;
    const f2* hlrow = reinterpret_cast<const f2*>(&hl_l[tid][0]);
    #pragma unroll
    for (int j = 0; j < 8; ++j) { f2 h = hlrow[j]; sh += h.x + h.y; }
    float cost = fmaf(beta_u[tid], 16.0f, sh) * S_l[tid];
    float z = LAMBDA * (beta_a[tid] - cost);
    float ao = __builtin_amdgcn_rcpf(1.0f + exp2_fast(-z * LOG2E));
    out[(size_t)n * 544 + 512 + tid] = ao;
  }
}

extern "C" void kernel_launch(void* const* d_in, const int* in_sizes, int n_in,
                              void* d_out, int out_size, void* d_ws, size_t ws_size,
                              hipStream_t stream) {
  const float* x  = (const float*)d_in[0];
  const float* w  = (const float*)d_in[1];
  const float* bu = (const float*)d_in[2];
  const float* ba = (const float*)d_in[3];
  float* out = (float*)d_out;
  convcaps_kernel<<<dim3(508), dim3(512), 0, stream>>>(x, w, bu, ba, out);
}

// Round 12
// 125.137 us; speedup vs baseline: 1.5832x; 1.5832x over previous
//
#include <hip/hip_runtime.h>
#include <math.h>

#define EPS 1e-8f
#define LAMBDA 1e-3f
#define LOG2E 1.44269504088896f
#define LN2 0.693147180559945f

typedef float f2 __attribute__((ext_vector_type(2)));
typedef unsigned int u32v2 __attribute__((ext_vector_type(2)));
__device__ __forceinline__ f2 f2s(float x) { return (f2){x, x}; }
__device__ __forceinline__ f2 pkfma(f2 a, f2 b, f2 c) {
  return __builtin_elementwise_fma(a, b, c);
}

// fast transcendentals (raw HW ops, log2 domain)
__device__ __forceinline__ float exp2_fast(float x) { float r; asm("v_exp_f32 %0, %1" : "=v"(r) : "v"(x)); return r; }
__device__ __forceinline__ float log2_fast(float x) { float r; asm("v_log_f32 %0, %1" : "=v"(r) : "v"(x)); return r; }

// DPP lane-permute: executes in the VALU pipe (no LDS round trip).
template <int CTRL>
__device__ __forceinline__ float dppmov(float v) {
  return __int_as_float(__builtin_amdgcn_update_dpp(
      0, __float_as_int(v), CTRL, 0xF, 0xF, true));
}

// xor16 / xor32 lane exchanges (gfx950 permlane*_swap = VALU; fallbacks portable)
#if __has_builtin(__builtin_amdgcn_permlane16_swap)
__device__ __forceinline__ float sum_x16(float v) {
  u32v2 r = __builtin_amdgcn_permlane16_swap(__float_as_uint(v), __float_as_uint(v), false, false);
  return __uint_as_float(r.x) + __uint_as_float(r.y);
}
__device__ __forceinline__ float max_x16(float v) {
  u32v2 r = __builtin_amdgcn_permlane16_swap(__float_as_uint(v), __float_as_uint(v), false, false);
  return fmaxf(__uint_as_float(r.x), __uint_as_float(r.y));
}
#else
__device__ __forceinline__ float sum_x16(float v) {
  return v + __int_as_float(__builtin_amdgcn_ds_swizzle(__float_as_int(v), 0x401F));
}
__device__ __forceinline__ float max_x16(float v) {
  return fmaxf(v, __int_as_float(__builtin_amdgcn_ds_swizzle(__float_as_int(v), 0x401F)));
}
#endif
#if __has_builtin(__builtin_amdgcn_permlane32_swap)
__device__ __forceinline__ float sum_x32(float v) {
  u32v2 r = __builtin_amdgcn_permlane32_swap(__float_as_uint(v), __float_as_uint(v), false, false);
  return __uint_as_float(r.x) + __uint_as_float(r.y);
}
#else
__device__ __forceinline__ float sum_x32(float v) { return v + __shfl_xor(v, 32, 64); }
#endif

__device__ __forceinline__ float redsum32(float v) {
  v += dppmov<0xB1>(v);    // xor 1
  v += dppmov<0x4E>(v);    // xor 2
  v += dppmov<0x141>(v);   // xor 7
  v += dppmov<0x140>(v);   // xor 15
  return sum_x16(v);       // xor 16
}
__device__ __forceinline__ float redmax32(float v) {
  v = fmaxf(v, dppmov<0xB1>(v));
  v = fmaxf(v, dppmov<0x4E>(v));
  v = fmaxf(v, dppmov<0x141>(v));
  v = fmaxf(v, dppmov<0x140>(v));
  return max_x16(v);
}

// 4x4 pose matmul on packed f2 lanes: v2[8] = x(4x4) @ w(4x4), row-major.
__device__ __forceinline__ void mat8(const float* __restrict__ xrow,
                                     float4 w0, float4 w1, float4 w2, float4 w3,
                                     f2 (&v2)[8]) {
  const float4* xp = reinterpret_cast<const float4*>(xrow);
  float4 xv0 = xp[0], xv1 = xp[1], xv2_ = xp[2], xv3 = xp[3];
  f2 w0a = {w0.x, w0.y}, w0b = {w0.z, w0.w};
  f2 w1a = {w1.x, w1.y}, w1b = {w1.z, w1.w};
  f2 w2a = {w2.x, w2.y}, w2b = {w2.z, w2.w};
  f2 w3a = {w3.x, w3.y}, w3b = {w3.z, w3.w};
  {
    f2 ta = f2s(xv0.x) * w0a; f2 tb = f2s(xv0.x) * w0b;
    ta = pkfma(f2s(xv0.y), w1a, ta); tb = pkfma(f2s(xv0.y), w1b, tb);
    ta = pkfma(f2s(xv0.z), w2a, ta); tb = pkfma(f2s(xv0.z), w2b, tb);
    v2[0] = pkfma(f2s(xv0.w), w3a, ta); v2[1] = pkfma(f2s(xv0.w), w3b, tb);
  }
  {
    f2 ta = f2s(xv1.x) * w0a; f2 tb = f2s(xv1.x) * w0b;
    ta = pkfma(f2s(xv1.y), w1a, ta); tb = pkfma(f2s(xv1.y), w1b, tb);
    ta = pkfma(f2s(xv1.z), w2a, ta); tb = pkfma(f2s(xv1.z), w2b, tb);
    v2[2] = pkfma(f2s(xv1.w), w3a, ta); v2[3] = pkfma(f2s(xv1.w), w3b, tb);
  }
  {
    f2 ta = f2s(xv2_.x) * w0a; f2 tb = f2s(xv2_.x) * w0b;
    ta = pkfma(f2s(xv2_.y), w1a, ta); tb = pkfma(f2s(xv2_.y), w1b, tb);
    ta = pkfma(f2s(xv2_.z), w2a, ta); tb = pkfma(f2s(xv2_.z), w2b, tb);
    v2[4] = pkfma(f2s(xv2_.w), w3a, ta); v2[5] = pkfma(f2s(xv2_.w), w3b, tb);
  }
  {
    f2 ta = f2s(xv3.x) * w0a; f2 tb = f2s(xv3.x) * w0b;
    ta = pkfma(f2s(xv3.y), w1a, ta); tb = pkfma(f2s(xv3.y), w1b, tb);
    ta = pkfma(f2s(xv3.z), w2a, ta); tb = pkfma(f2s(xv3.z), w2b, tb);
    v2[6] = pkfma(f2s(xv3.w), w3a, ta); v2[7] = pkfma(f2s(xv3.w), w3b, tb);
  }
}

template <bool V> struct BoolC { static constexpr bool value = V; };

// One block per output row n (508 rows). 512 threads = 16 chunks x 32 c.
// Thread (chunk,c) owns output capsule c for B in [chunk*18, chunk*18+18).
//
// ROUND-12: round-8 structure (scalar red[33][256] stores -- ds_write_b32,
// NO b64 pairing constraint on the long-lived A1/A2 accumulators; rounds
// 9-11's f2 red2 b64 stores forced 16 even-aligned VGPR pairs live across
// the whole 18-iter loop -> regfile fragmentation -> 128-cap spill) plus
// the register-neutral wins verified in rounds 9-11:
//   (a) per-pass aout/lnao section + its barrier DELETED; lnao computed
//       inline in bias-prep (2 trans ops); a_out once at kernel end.
//
// launch_bounds(512, 2): empirically caps VGPR at 128 (2 blocks/CU);
// (512,4) forced a 64-cap and spilled (rounds 0-2). Spills show as
// WRITE_SIZE above the 19.4 MB output floor / FETCH above ~5 MB.
__launch_bounds__(512, 2)
__global__ void convcaps_kernel(const float* __restrict__ x,
                                const float* __restrict__ wgl,
                                const float* __restrict__ beta_u,
                                const float* __restrict__ beta_a,
                                float* __restrict__ out) {
  __shared__ float xr[288][16];       // pose patches, 18 KB
  __shared__ float a_sh[288];         // a/(a+EPS)
  __shared__ float red[33][256];      // per-wave partials (A1[16],A2[16],S) -- SCALAR stores
  __shared__ float mu_l[32][18];      // +2 pad: rows 8B-aligned for b64 reads
  __shared__ float i2s_l[32][18];     // LOG2E/(2*sigma)
  __shared__ float hl_l[32][18];      // 0.5*ln(sigma)
  __shared__ float S_l[32];

  const int tid = threadIdx.x;
  const int n = blockIdx.x;
  const int c = tid & 31;
  const int chunk = tid >> 5;         // 0..15

  // ---- stage 9 source rows (float4): xr[B][s], a_sh[B] ----
  for (int idx = tid; idx < 1224; idx += 512) {   // 9 * 136 float4
    int t = idx / 136;
    int e4 = idx - t * 136;
    int g = 9 * n + t;
    int bg = g / 2286;                 // 2286 = 9*254
    int ki = (g % 2286) / 762;         // 762 = 3*254
    int owp = g % 254;
    const float4* src = reinterpret_cast<const float4*>(x) +
                        (size_t)((bg * 256 + ki + owp) * 4) * 136;
    float4 val = src[e4];
    if (e4 < 128) reinterpret_cast<float4*>(&xr[0][0])[t * 128 + e4] = val;
    else          reinterpret_cast<float4*>(a_sh)[t * 8 + (e4 - 128)] = val;
  }
  __syncthreads();
  for (int e = tid; e < 288; e += 512) { float a = a_sh[e]; a_sh[e] = a / (a + EPS); }
  __syncthreads();

  f2 A1[8], A2[8];
  float Ssum;
  f2 m2[8], i2s2[8];                  // m2 = -2*mu*i2s; i2s pre-scaled LOG2E
  float bias3 = 0.f;
  const int Bbase = chunk * 18;
  const float4* wp = reinterpret_cast<const float4*>(wgl) + ((size_t)(Bbase * 32 + c)) * 4;
  float* rowout = out + 276352 + ((size_t)n * 288 + Bbase) * 32 + c;   // r output

  auto ldw = [&](int i, float4& b0, float4& b1, float4& b2, float4& b3) {
    const float4* nx = wp + (size_t)i * 128;
    b0 = nx[0]; b1 = nx[1]; b2 = nx[2]; b3 = nx[3];
  };

  auto accum = [&](const f2 (&v2)[8], float wgt) {
    f2 wg = f2s(wgt);
    #pragma unroll
    for (int j = 0; j < 8; ++j) {
      f2 p = wg * v2[j];
      A1[j] += p;
      A2[j] = pkfma(p, v2[j], A2[j]);
    }
    Ssum += wgt;
  };

  auto qexp = [&](const f2 (&v2)[8]) -> float {
    f2 qa = {0.f, 0.f}, qb = {0.f, 0.f};
    #pragma unroll
    for (int j = 0; j < 8; j += 2) {
      f2 t0 = pkfma(v2[j], i2s2[j], m2[j]);
      qa = pkfma(v2[j], t0, qa);
      f2 t1 = pkfma(v2[j + 1], i2s2[j + 1], m2[j + 1]);
      qb = pkfma(v2[j + 1], t1, qb);
    }
    float acc = (qa.x + qb.x) + (qa.y + qb.y);
    return exp2_fast(bias3 - acc);      // lnap <= 0, log2 domain
  };

  // finalize: 2 barriers (red publish, stats publish). No aout section.
  auto finalize = [&]() {
    #pragma unroll
    for (int j = 0; j < 8; ++j) {
      A1[j].x = sum_x32(A1[j].x);
      A1[j].y = sum_x32(A1[j].y);
      A2[j].x = sum_x32(A2[j].x);
      A2[j].y = sum_x32(A2[j].y);
    }
    Ssum = sum_x32(Ssum);
    if ((tid & 63) < 32) {
      int col = (tid >> 6) * 32 + c;
      #pragma unroll
      for (int j = 0; j < 8; ++j) {     // SCALAR stores: no VGPR pairing
        red[2 * j][col] = A1[j].x;
        red[2 * j + 1][col] = A1[j].y;
        red[16 + 2 * j][col] = A2[j].x;
        red[17 + 2 * j][col] = A2[j].y;
      }
      red[32][col] = Ssum;
    }
    __syncthreads();
    {
      int s = tid >> 5;
      int c2 = tid & 31;
      float a1 = 0.f, a2 = 0.f, ss = 0.f;
      #pragma unroll
      for (int ch = 0; ch < 8; ++ch) {
        int col = ch * 32 + c2;
        a1 += red[s][col];
        a2 += red[16 + s][col];
        ss += red[32][col];
      }
      float inv = __builtin_amdgcn_rcpf(ss + EPS);
      float m = a1 * inv;
      float Sc = ss * inv;
      float sg = fmaf(-m * m, 2.0f - Sc, a2 * inv) + EPS;   // sigma_sq
      mu_l[c2][s] = m;
      i2s_l[c2][s] = (0.5f * LOG2E) * __builtin_amdgcn_rcpf(sg);  // log2 domain
      hl_l[c2][s] = 0.5f * __logf(sg);
      if (s == 0) S_l[c2] = ss;
    }
    __syncthreads();
  };

  // ================= pass 0: wgt = a/32, no softmax =================
  {
    #pragma unroll
    for (int j = 0; j < 8; ++j) { A1[j] = (f2){0.f, 0.f}; A2[j] = (f2){0.f, 0.f}; }
    Ssum = 0.f;
    #pragma unroll
    for (int i = 0; i < 18; ++i) {
      float4 w0, w1, w2, w3;
      ldw(i, w0, w1, w2, w3);
      f2 v2[8];
      mat8(&xr[Bbase + i][0], w0, w1, w2, w3, v2);
      accum(v2, a_sh[Bbase + i] * 0.03125f);
    }
    finalize();
  }

  // ================= passes 1,2: fully-unrolled softmax loop =================
  auto em_pass = [&](auto storeC) {
    constexpr bool doStore = decltype(storeC)::value;
    #pragma unroll
    for (int j = 0; j < 8; ++j) { A1[j] = (f2){0.f, 0.f}; A2[j] = (f2){0.f, 0.f}; }
    Ssum = 0.f;
    {
      const f2* murow = reinterpret_cast<const f2*>(&mu_l[c][0]);
      const f2* isrow = reinterpret_cast<const f2*>(&i2s_l[c][0]);
      f2 kacc = {0.f, 0.f};
      float Hl = 0.f;
      #pragma unroll
      for (int j = 0; j < 8; ++j) {
        f2 mu = murow[j];
        f2 is = isrow[j];
        i2s2[j] = is;
        f2 mis = mu * is;
        m2[j] = f2s(-2.f) * mis;
        kacc = pkfma(mis, mu, kacc);        // sum mu^2*i2s (log2 domain)
        Hl += hl_l[c][2 * j] + hl_l[c][2 * j + 1];
      }
      // inline ln(a_out): cost=(bu*16+Hl)*S; lnao = -ln(1+exp(-z)) via log2
      float S = S_l[c];
      float cost = fmaf(beta_u[c], 16.0f, Hl) * S;
      float z = LAMBDA * (beta_a[c] - cost);
      float u = 1.0f + exp2_fast(-z * LOG2E);
      float lnao = -LN2 * log2_fast(u);
      float bias = lnao - Hl;
      bias -= redmax32(bias);               // once per pass: lnap <= 0 always
      bias3 = bias * LOG2E - (kacc.x + kacc.y);
    }

    f2 vb0[8], vb1[8];                      // parity banks, literal-indexed
    float wg0 = 0.f, wg1 = 0.f;
    #pragma unroll
    for (int i = 0; i < 18; ++i) {          // i is a literal after unroll
      f2 (&v2)[8] = (i & 1) ? vb1 : vb0;
      float4 w0, w1, w2, w3;
      ldw(i, w0, w1, w2, w3);
      mat8(&xr[Bbase + i][0], w0, w1, w2, w3, v2);
      float af = a_sh[Bbase + i];
      float e = qexp(v2);
      float se = redsum32(e);
      if (i > 0) {                          // fill the reduce's dep shadow
        f2 (&pv)[8] = ((i - 1) & 1) ? vb1 : vb0;
        accum(pv, ((i - 1) & 1) ? wg1 : wg0);
      }
      float t = __builtin_amdgcn_rcpf(se + 1e-35f);
      float r2 = e * t;
      if (doStore) rowout[(size_t)i * 32] = r2;
      ((i & 1) ? wg1 : wg0) = r2 * af;
    }
    accum(vb1, wg1);                        // i = 17 is odd -> bank 1
    finalize();
  };
  em_pass(BoolC<false>{});
  em_pass(BoolC<true>{});

  // ---- outputs: row n = [mu (512) | a_out (32)], coalesced ----
  {
    int c2 = tid >> 4;
    int s = tid & 15;
    out[(size_t)n * 544 + tid] = mu_l[c2][s];
  }
  if (tid < 32) {                     // a_out from pass-2 stats (c == tid)
    float sh = 0.f;
    #pragma unroll
    for (int s = 0; s < 16; ++s) sh += hl_l[tid][s];
    float cost = fmaf(beta_u[tid], 16.0f, sh) * S_l[tid];
    float z = LAMBDA * (beta_a[tid] - cost);
    float ao = __builtin_amdgcn_rcpf(1.0f + exp2_fast(-z * LOG2E));
    out[(size_t)n * 544 + 512 + tid] = ao;
  }
}

extern "C" void kernel_launch(void* const* d_in, const int* in_sizes, int n_in,
                              void* d_out, int out_size, void* d_ws, size_t ws_size,
                              hipStream_t stream) {
  const float* x  = (const float*)d_in[0];
  const float* w  = (const float*)d_in[1];
  const float* bu = (const float*)d_in[2];
  const float* ba = (const float*)d_in[3];
  float* out = (float*)d_out;
  convcaps_kernel<<<dim3(508), dim3(512), 0, stream>>>(x, w, bu, ba, out);
}